// Round 1
// baseline (5159.253 us; speedup 1.0000x reference)
//
#include <hip/hip_runtime.h>

// Problem constants (from reference setup_inputs)
#define T_TOK   32768
#define N_SLOTS 128
#define D_DIM   4096
#define B_DIM   4

// sums kernel tiling
#define W_SLICE 128                       // D columns per block
#define C_TOK   2048                      // tokens per block
#define MAIN_THREADS 1024
#define N_SLICES (D_DIM / W_SLICE)        // 32
#define N_CHUNKS (T_TOK / C_TOK)          // 16
#define ROWS_PER_ITER (MAIN_THREADS / (W_SLICE / 4))  // 32 token rows per block-iter

typedef unsigned long long u64;

// ws layout
#define SUMS_BYTES   ((size_t)N_SLOTS * D_DIM * sizeof(float))   // 2 MiB
#define COUNTS_OFF   SUMS_BYTES
#define PACKED_OFF   (SUMS_BYTES + 512)                          // 128*4 counts, pad to 512
#define ZERO_BYTES   PACKED_OFF                                  // zero sums+counts each call

// ---------------------------------------------------------------------------
// Kernel 1: dedup slot indices per token -> packed u64 (byte = slot or 0xFF),
// and accumulate counts[n] (distinct-per-token semantics).
// ---------------------------------------------------------------------------
__global__ __launch_bounds__(256) void prep_kernel(const int* __restrict__ sidx,
                                                   u64* __restrict__ packed,
                                                   int* __restrict__ counts) {
  __shared__ int cnt[N_SLOTS];
  const int tid = threadIdx.x;
  if (tid < N_SLOTS) cnt[tid] = 0;
  __syncthreads();

  const int t = blockIdx.x * 256 + tid;   // grid exactly covers T_TOK
  const int4 a = ((const int4*)sidx)[2 * t];
  const int4 b = ((const int4*)sidx)[2 * t + 1];
  int idx[8] = {a.x, a.y, a.z, a.w, b.x, b.y, b.z, b.w};

  u64 pk = 0;
  #pragma unroll
  for (int k = 0; k < 8; ++k) {
    int n = idx[k];
    bool dup = false;
    #pragma unroll
    for (int j = 0; j < 8; ++j)
      if (j < k) dup |= (idx[j] == n);
    u64 byte = (dup || (unsigned)n >= (unsigned)N_SLOTS) ? 0xFFull : (u64)(unsigned)n;
    pk |= byte << (8 * k);
    if (byte != 0xFFull) atomicAdd(&cnt[n], 1);
  }
  packed[t] = pk;

  __syncthreads();
  if (tid < N_SLOTS && cnt[tid] > 0) atomicAdd(&counts[tid], cnt[tid]);
}

// ---------------------------------------------------------------------------
// Kernel 2: the 512 MB stream. Each block: one 128-wide D-slice x 2048 tokens.
// LDS acc[n] stored transposed per slot row: word = n*128 + c*32 + col
// (c = float4 component, col = thread column). ds_add_f32 banks = col -> 2-way.
// ---------------------------------------------------------------------------
__global__ __launch_bounds__(MAIN_THREADS) void sums_kernel(const float* __restrict__ hidden,
                                                            const u64* __restrict__ packed,
                                                            float* __restrict__ sums) {
  __shared__ float acc[N_SLOTS * W_SLICE];   // 64 KiB
  const int tid = threadIdx.x;
  #pragma unroll
  for (int i = 0; i < (N_SLOTS * W_SLICE) / MAIN_THREADS; ++i)
    acc[i * MAIN_THREADS + tid] = 0.0f;
  __syncthreads();

  const int slice = blockIdx.x & (N_SLICES - 1);
  const int chunk = blockIdx.x / N_SLICES;
  const int d0 = slice * W_SLICE;
  const int col = tid & 31;      // float4 column within slice
  const int r   = tid >> 5;      // token row within iter group (0..31)
  const float4* __restrict__ h4 = (const float4*)hidden;
  const size_t rowStride4 = D_DIM / 4;

  int t = chunk * C_TOK + r;
  #pragma unroll 2
  for (int it = 0; it < C_TOK / ROWS_PER_ITER; ++it, t += ROWS_PER_ITER) {
    float4 h = h4[(size_t)t * rowStride4 + (d0 >> 2) + col];
    u64 pk = packed[t];
    #pragma unroll
    for (int k = 0; k < 8; ++k) {
      int n = (int)((pk >> (8 * k)) & 0xFF);
      if (n < N_SLOTS) {
        float* base = &acc[(n << 7) + col];
        unsafeAtomicAdd(base,      h.x);   // ds_add_f32, offset-immediate folded
        unsafeAtomicAdd(base + 32, h.y);
        unsafeAtomicAdd(base + 64, h.z);
        unsafeAtomicAdd(base + 96, h.w);
      }
    }
  }
  __syncthreads();

  // Flush LDS partial sums to global ws sums (L2-resident, 2 MiB) via f32 atomics.
  #pragma unroll
  for (int i = 0; i < (N_SLOTS * W_SLICE) / MAIN_THREADS; ++i) {
    int w = i * MAIN_THREADS + tid;
    int n = w >> 7;
    int p = w & 127;
    int x = ((p & 31) << 2) | (p >> 5);   // logical column within slice
    unsafeAtomicAdd(&sums[(size_t)n * D_DIM + d0 + x], acc[w]);
  }
}

// ---------------------------------------------------------------------------
// Kernel 3: out = memory, with row batch_idx blended:
//   counts>0 ? 0.1*sums/counts + 0.9*cur : cur
// ---------------------------------------------------------------------------
__global__ __launch_bounds__(256) void final_kernel(const float* __restrict__ memory,
                                                    const float* __restrict__ sums,
                                                    const int* __restrict__ counts,
                                                    const int* __restrict__ bidx_p,
                                                    float* __restrict__ out) {
  const size_t i = (size_t)blockIdx.x * 256 + threadIdx.x;   // float4 index
  float4 v = ((const float4*)memory)[i];
  const size_t rowLen4 = (size_t)N_SLOTS * (D_DIM / 4);
  const size_t rowStart = (size_t)(*bidx_p) * rowLen4;
  if (i >= rowStart && i < rowStart + rowLen4) {
    const size_t rel = i - rowStart;
    const int n  = (int)(rel / (D_DIM / 4));
    const int d4 = (int)(rel % (D_DIM / 4));
    const int c = counts[n];
    if (c > 0) {
      float4 s = ((const float4*)sums)[(size_t)n * (D_DIM / 4) + d4];
      const float w = 0.1f / (float)c;
      v.x = s.x * w + 0.9f * v.x;
      v.y = s.y * w + 0.9f * v.y;
      v.z = s.z * w + 0.9f * v.z;
      v.w = s.w * w + 0.9f * v.w;
    }
  }
  ((float4*)out)[i] = v;
}

extern "C" void kernel_launch(void* const* d_in, const int* in_sizes, int n_in,
                              void* d_out, int out_size, void* d_ws, size_t ws_size,
                              hipStream_t stream) {
  const float* memory = (const float*)d_in[0];
  const float* hidden = (const float*)d_in[1];
  const int*   sidx   = (const int*)d_in[2];
  const int*   bidx   = (const int*)d_in[3];
  float* out = (float*)d_out;

  char* ws = (char*)d_ws;
  float* sums   = (float*)ws;
  int*   counts = (int*)(ws + COUNTS_OFF);
  u64*   packed = (u64*)(ws + PACKED_OFF);

  // zero sums + counts (packed is fully overwritten by prep)
  hipMemsetAsync(ws, 0, ZERO_BYTES, stream);

  prep_kernel<<<T_TOK / 256, 256, 0, stream>>>(sidx, packed, counts);

  sums_kernel<<<N_CHUNKS * N_SLICES, MAIN_THREADS, 0, stream>>>(hidden, packed, sums);

  const int totalVec4 = B_DIM * N_SLOTS * (D_DIM / 4);   // 524288
  final_kernel<<<totalVec4 / 256, 256, 0, stream>>>(memory, sums, counts, bidx, out);
}